// Round 5
// baseline (1584.176 us; speedup 1.0000x reference)
//
#include <hip/hip_runtime.h>

#define DIM   4096
#define NTOK  8192
#define NH    32
#define HD    128

typedef _Float16 f16x8  __attribute__((ext_vector_type(8)));
typedef float    f32x4  __attribute__((ext_vector_type(4)));
typedef float    f32x16 __attribute__((ext_vector_type(16)));

__device__ __forceinline__ unsigned short f2h(float f) {
    _Float16 h = (_Float16)f;                    // RTNE
    return __builtin_bit_cast(unsigned short, h);
}
__device__ __forceinline__ float h2f(unsigned short u) {
    return (float)__builtin_bit_cast(_Float16, u);
}

// async 16B/lane global->LDS. LDS dest is wave-uniform base; HW scatters lane L to base + 16*L.
__device__ __forceinline__ void async_ld16(const unsigned short* g, unsigned short* l) {
    __builtin_amdgcn_global_load_lds(
        (const __attribute__((address_space(1))) unsigned int*)g,
        (__attribute__((address_space(3))) unsigned int*)l,
        16, 0, 0);
}

// ---------------------------------------------------------------------------
// x fp32 -> f16, elementwise. 8 elems/thread.
// ---------------------------------------------------------------------------
__global__ __launch_bounds__(256)
void convert_x(const float* __restrict__ in, unsigned short* __restrict__ out) {
    const size_t i = ((size_t)blockIdx.x * 256 + threadIdx.x) * 8;
    float4 a = *(const float4*)(in + i);
    float4 b = *(const float4*)(in + i + 4);
    ushort4 o0 = { f2h(a.x), f2h(a.y), f2h(a.z), f2h(a.w) };
    ushort4 o1 = { f2h(b.x), f2h(b.y), f2h(b.z), f2h(b.w) };
    *(ushort4*)(out + i)     = o0;
    *(ushort4*)(out + i + 4) = o1;
}

// ---------------------------------------------------------------------------
// W fp32 [k][n] -> Wt f16 [n][k], 4096x4096
// ---------------------------------------------------------------------------
__global__ __launch_bounds__(256)
void transpose_cvt4k(const float* __restrict__ in, unsigned short* __restrict__ out) {
    __shared__ unsigned short tile[32][33];
    const int tx = threadIdx.x & 31;
    const int ty = threadIdx.x >> 5;       // 0..7
    const int n0 = blockIdx.x * 32;
    const int k0 = blockIdx.y * 32;
#pragma unroll
    for (int i = 0; i < 4; ++i)
        tile[ty + i * 8][tx] = f2h(in[(size_t)(k0 + ty + i * 8) * DIM + n0 + tx]);
    __syncthreads();
#pragma unroll
    for (int i = 0; i < 4; ++i)
        out[(size_t)(n0 + ty + i * 8) * DIM + k0 + tx] = tile[tx][ty + i * 8];
}

// ---------------------------------------------------------------------------
// NT GEMM, 256x256 tile, BK=64, 8 waves (2Mx4N), pipelined cluster schedule,
// persistent-pair blocks.  Round-4 change: MFMA shape 16x16x32 -> 32x32x16
// (m119: 2495 vs 2075 TF pipe rate, half the MFMA instruction count).
//
// Wave tile 128x64 = 4 m-frags x 2 n-frags of 32x32, K=64 = 4 k-slices of 16.
// A/B frag layout: row = lane&31, k = (lane>>5)*8 + j  (4 VGPR, 8 f16/lane).
// C/D frag layout (HW-verified m74/m101): col = lane&31,
//   row = (reg&3) + 8*(reg>>2) + 4*(lane>>5), reg in [0,16).
// Bank conflicts: per 16-lane quarter-group, 16 consecutive rows at fixed
// 16B column; (row&7)<<3 XOR swizzle -> 8 slots x 2 lanes = 2-way = free
// (same profile as the 16x16 version; conflicts measured 0).
//
// Schedule/staging/barriers identical to round-3 (lifetime proofs carry over:
// B consumed entirely at tile start -> STB after barrier#1; A m-frags 0-1
// consumed before barrier#2 -> STA after barrier#2; vmcnt(6) once per tile).
// ---------------------------------------------------------------------------
#define BARRIER() do { __builtin_amdgcn_sched_barrier(0); \
                       __builtin_amdgcn_s_barrier();      \
                       __builtin_amdgcn_sched_barrier(0); } while (0)
#define VMCNT6()  asm volatile("s_waitcnt vmcnt(6)" ::: "memory")

__device__ __forceinline__ void mfma_c32(f32x16 (&accr)[2],
                                         const f16x8 (&aF)[4],
                                         const f16x8 (&bF)[2][4]) {
    __builtin_amdgcn_s_setprio(1);
#pragma unroll
    for (int ks = 0; ks < 4; ++ks)
#pragma unroll
        for (int n = 0; n < 2; ++n)
            accr[n] = __builtin_amdgcn_mfma_f32_32x32x16_f16(aF[ks], bF[n][ks], accr[n], 0, 0, 0);
    __builtin_amdgcn_s_setprio(0);
}

template <int OUT_F16>
__global__ __launch_bounds__(512, 2)
void gemm_nt_256(const unsigned short* __restrict__ A,
                 const unsigned short* __restrict__ Bt,
                 void* __restrict__ C, int M, int N, int K) {
    __shared__ unsigned short sA[2 * 256 * 64];   // 64 KiB
    __shared__ unsigned short sB[2 * 256 * 64];   // 64 KiB

    // persistent-pair mapping: nwg = (M/256)*(N/256)/2 blocks, pair along M.
    const int bid     = blockIdx.x;
    const int per_xcd = gridDim.x >> 3;           // 32
    const int wg      = (bid & 7) * per_xcd + (bid >> 3);
    const int m_pairs = M >> 9;                   // 16
    const int n_idx   = wg / m_pairs;
    const int m_pair  = wg % m_pairs;
    const int n0      = n_idx * 256;

    const int t    = threadIdx.x;
    const int w    = t >> 6;
    const int lane = t & 63;
    const int wm   = w >> 2;              // 0..1  (128 rows of C per wave)
    const int wn   = w & 3;               // 0..3  (64 cols of C per wave)
    const int fr   = lane & 31;           // fragment row (32x32)
    const int kq   = (lane >> 5) << 3;    // lane's k offset within 16 (f16 units)
    const int swz  = (fr & 7) << 3;       // read-side swizzle (shorts)
    // k-slice read offsets (shorts), swizzled; ks*16 + kq in bits 3..5, XOR safe
    const int co0  = (0  + kq) ^ swz;
    const int co1  = (16 + kq) ^ swz;
    const int co2  = (32 + kq) ^ swz;
    const int co3  = (48 + kq) ^ swz;

    // staging: thread t covers LDS (row = t>>3 within slab, chunk = t&7).
    // Source chunk pre-swizzled so linear LDS + swizzled ds_read match.
    const int rowt = t >> 3;
    const int cSw8 = ((t & 7) ^ (rowt & 7)) << 3;
    unsigned short* dA = sA + w * 512;    // wave-uniform LDS base (1 KiB/wave/slab)
    unsigned short* dB = sB + w * 512;
    const unsigned short* pA0 = sA + (wm * 128 + fr) * 64;
    const unsigned short* pB0 = sB + (wn * 64  + fr) * 64;

    const int KT = K >> 6;                // 64 K-tiles

    f32x16 acc[4][2];
    f16x8  aC[4], aN[4], bF[2][4];

#define STA(srcT, dpar, r0) async_ld16(gA + (size_t)(r0) * K + (size_t)(srcT) * 64, \
                                       dA + (dpar) * 16384 + (r0) * 64)
#define STB(srcT, dpar, r0) async_ld16(gB + (size_t)(r0) * K + (size_t)(srcT) * 64, \
                                       dB + (dpar) * 16384 + (r0) * 64)
#define LDF(p, off) (*(const f16x8*)(const void*)((p) + (off)))

    for (int tt = 0; tt < 2; ++tt) {
        const int m0 = (m_pair * 2 + tt) * 256;
        const unsigned short* gA = A  + (size_t)(m0 + rowt) * K + cSw8;
        const unsigned short* gB = Bt + (size_t)(n0 + rowt) * K + cSw8;

#pragma unroll
        for (int i = 0; i < 4; ++i)
#pragma unroll
            for (int j = 0; j < 2; ++j) acc[i][j] = (f32x16)(0.f);

        // prologue: tile0 complete (8 slabs) + tile1 {Bx4, A rows 0-63/128-191}.
        // For tt=1 issued AFTER tile0's C-stores: vmcnt(6) drains stores +
        // oldest 8 loads, leaving exactly the 6 partials.
        STA(0, 0, 0); STA(0, 0, 64); STA(0, 0, 128); STA(0, 0, 192);
        STB(0, 0, 0); STB(0, 0, 64); STB(0, 0, 128); STB(0, 0, 192);
        STB(1, 1, 0); STB(1, 1, 64); STB(1, 1, 128); STB(1, 1, 192);
        STA(1, 1, 0); STA(1, 1, 128);
        VMCNT6();
        BARRIER();

#define KTILE(T, BUF) do {                                                        \
    const int T1c = ((T) + 1 < KT) ? (T) + 1 : KT - 1;  /* clamp: dest never read */ \
    const int T2c = ((T) + 2 < KT) ? (T) + 2 : KT - 1;                            \
    const unsigned short* pa = pA0 + (BUF) * 16384;                               \
    const unsigned short* pb = pB0 + (BUF) * 16384;                               \
    /* tile start: full B (8 reads) + A m-frag0 (4 reads); stage A'(T+1) */       \
    bF[0][0] = LDF(pb,        co0); bF[0][1] = LDF(pb,        co1);               \
    bF[0][2] = LDF(pb,        co2); bF[0][3] = LDF(pb,        co3);               \
    bF[1][0] = LDF(pb, 2048 + co0); bF[1][1] = LDF(pb, 2048 + co1);               \
    bF[1][2] = LDF(pb, 2048 + co2); bF[1][3] = LDF(pb, 2048 + co3);               \
    aC[0] = LDF(pa, co0); aC[1] = LDF(pa, co1);                                   \
    aC[2] = LDF(pa, co2); aC[3] = LDF(pa, co3);                                   \
    STA(T1c, (BUF) ^ 1, 64); STA(T1c, (BUF) ^ 1, 192);                            \
    mfma_c32(acc[0], aC, bF);                                                     \
    /* prefetch m-frag1 during cluster0 */                                        \
    aN[0] = LDF(pa, 2048 + co0); aN[1] = LDF(pa, 2048 + co1);                     \
    aN[2] = LDF(pa, 2048 + co2); aN[3] = LDF(pa, 2048 + co3);                     \
    BARRIER();  /* #1: B reads drained (tile start) before B staging lands */     \
    STB(T2c, (BUF), 0);   STB(T2c, (BUF), 64);                                    \
    STB(T2c, (BUF), 128); STB(T2c, (BUF), 192);                                   \
    mfma_c32(acc[1], aN, bF);                                                     \
    /* prefetch m-frag2 during cluster1 */                                        \
    aC[0] = LDF(pa, 4096 + co0); aC[1] = LDF(pa, 4096 + co1);                     \
    aC[2] = LDF(pa, 4096 + co2); aC[3] = LDF(pa, 4096 + co3);                     \
    BARRIER();  /* #2: A m-frags 0-1 consumed before A staging lands */           \
    STA(T2c, (BUF), 0); STA(T2c, (BUF), 128);                                     \
    mfma_c32(acc[2], aC, bF);                                                     \
    /* prefetch m-frag3 during cluster2 (rows never staged in-tile) */            \
    aN[0] = LDF(pa, 6144 + co0); aN[1] = LDF(pa, 6144 + co1);                     \
    aN[2] = LDF(pa, 6144 + co2); aN[3] = LDF(pa, 6144 + co3);                     \
    mfma_c32(acc[3], aN, bF);                                                     \
    VMCNT6();                                                                     \
    BARRIER();  /* #3: closing — next tile's reads see drained staging */         \
} while (0)

        for (int it = 0; it < (KT >> 1); ++it) {
            const int kt = it << 1;
            KTILE(kt, 0);
            KTILE(kt + 1, 1);
        }
#undef KTILE

        // epilogue: C/D layout col = lane&31, row = (reg&3)+8*(reg>>2)+4*(lane>>5)
        const int col0 = n0 + wn * 64 + (lane & 31);
        const int row0 = m0 + wm * 128 + 4 * (lane >> 5);
#pragma unroll
        for (int mf = 0; mf < 4; ++mf) {
#pragma unroll
            for (int nf = 0; nf < 2; ++nf) {
#pragma unroll
                for (int r = 0; r < 16; ++r) {
                    const size_t row = (size_t)(row0 + mf * 32 + (r & 3) + 8 * (r >> 2));
                    const size_t idx = row * (size_t)N + (size_t)(col0 + nf * 32);
                    if (OUT_F16) ((unsigned short*)C)[idx] = f2h(acc[mf][nf][r]);
                    else         ((float*)C)[idx]          = acc[mf][nf][r];
                }
            }
        }
    }
#undef STA
#undef STB
#undef LDF
}

// ---------------------------------------------------------------------------
// Per-token head-mixing attention: S = Q Kt (32x32), softmax rows, y = S V.
// One block per token. Q,K fp32 (precision), V f16, y f16.
// sQ/sK float4-slot XOR-swizzle p = c ^ ((row>>1)&7) — removed the 16-way
// score-phase bank conflict (1.34e8 -> ~0 conflict-cycles, round-1 verified).
// ---------------------------------------------------------------------------
__global__ __launch_bounds__(256)
void attn_kernel(const float* __restrict__ Q, const float* __restrict__ K,
                 const unsigned short* __restrict__ V, unsigned short* __restrict__ Y) {
    __shared__ float sQ[NH * HD];               // 16 KB (float4-slot swizzled)
    __shared__ float sK[NH * HD];               // 16 KB (float4-slot swizzled)
    __shared__ unsigned short sV[NH * HD];      // 8 KB
    __shared__ float sS[NH * 33];               // 32x33 (padded)

    const int n = blockIdx.x;
    const int t = threadIdx.x;
    const size_t base = (size_t)n * DIM;

    const float4* gQ = (const float4*)(Q + base);
    const float4* gK = (const float4*)(K + base);
#pragma unroll
    for (int i = 0; i < 4; ++i) {
        const int f = t + 256 * i;
        const int r = f >> 5;                   // row 0..31
        const int p = (f & 31) ^ ((r >> 1) & 7);  // swizzled float4 slot
        ((float4*)sQ)[r * 32 + p] = gQ[f];
        ((float4*)sK)[r * 32 + p] = gK[f];
    }
    const float4* gV = (const float4*)(V + base);
#pragma unroll
    for (int i = 0; i < 2; ++i)
        ((float4*)sV)[t + 256 * i] = gV[t + 256 * i];
    __syncthreads();

    // scores: 16x16 thread grid, each thread a 2x2 block of S
    {
        const int th = (t >> 4) * 2;
        const int tg = (t & 15) * 2;
        const int sq = (th >> 1) & 7;           // th, th+1 share (th even)
        const int sk = (tg >> 1) & 7;
        float s00 = 0.f, s01 = 0.f, s10 = 0.f, s11 = 0.f;
        const float4* q0 = (const float4*)(sQ + th * HD);
        const float4* q1 = (const float4*)(sQ + (th + 1) * HD);
        const float4* k0 = (const float4*)(sK + tg * HD);
        const float4* k1 = (const float4*)(sK + (tg + 1) * HD);
#pragma unroll 4
        for (int d = 0; d < HD / 4; ++d) {
            float4 a0 = q0[d ^ sq], a1 = q1[d ^ sq];
            float4 b0 = k0[d ^ sk], b1 = k1[d ^ sk];
            s00 += a0.x * b0.x + a0.y * b0.y + a0.z * b0.z + a0.w * b0.w;
            s01 += a0.x * b1.x + a0.y * b1.y + a0.z * b1.z + a0.w * b1.w;
            s10 += a1.x * b0.x + a1.y * b0.y + a1.z * b0.z + a1.w * b0.w;
            s11 += a1.x * b1.x + a1.y * b1.y + a1.z * b1.z + a1.w * b1.w;
        }
        sS[th * 33 + tg] = s00;       sS[th * 33 + tg + 1] = s01;
        sS[(th + 1) * 33 + tg] = s10; sS[(th + 1) * 33 + tg + 1] = s11;
    }
    __syncthreads();

    if (t < NH) {                      // row softmax (no 1/sqrt(d) scale — faithful to ref)
        float m = -1e30f;
        for (int g = 0; g < NH; ++g) m = fmaxf(m, sS[t * 33 + g]);
        float sum = 0.f;
        for (int g = 0; g < NH; ++g) { float e = __expf(sS[t * 33 + g] - m); sS[t * 33 + g] = e; sum += e; }
        float inv = 1.f / sum;
        for (int g = 0; g < NH; ++g) sS[t * 33 + g] *= inv;
    }
    __syncthreads();

    // y[h][d] = sum_g S[h][g] * V[g][d]; thread task: 2 heads x 4 d
#pragma unroll
    for (int e = 0; e < 2; ++e) {
        const int task = t + e * 256;          // 0..511
        const int h0 = (task >> 5) * 2;        // heads h0, h0+1
        const int dg = (task & 31) * 4;        // d offset
        float a0x = 0, a0y = 0, a0z = 0, a0w = 0;
        float a1x = 0, a1y = 0, a1z = 0, a1w = 0;
#pragma unroll 4
        for (int g = 0; g < NH; ++g) {
            ushort4 uv = *(const ushort4*)(const void*)(sV + g * HD + dg);
            float vx = h2f(uv.x), vy = h2f(uv.y), vz = h2f(uv.z), vw = h2f(uv.w);
            float p0 = sS[h0 * 33 + g], p1 = sS[(h0 + 1) * 33 + g];
            a0x += p0 * vx; a0y += p0 * vy; a0z += p0 * vz; a0w += p0 * vw;
            a1x += p1 * vx; a1y += p1 * vy; a1z += p1 * vz; a1w += p1 * vw;
        }
        ushort4 o0 = { f2h(a0x), f2h(a0y), f2h(a0z), f2h(a0w) };
        ushort4 o1 = { f2h(a1x), f2h(a1y), f2h(a1z), f2h(a1w) };
        *(ushort4*)(void*)(Y + base + (size_t)h0 * HD + dg)       = o0;
        *(ushort4*)(void*)(Y + base + (size_t)(h0 + 1) * HD + dg) = o1;
    }
}

// ---------------------------------------------------------------------------
extern "C" void kernel_launch(void* const* d_in, const int* in_sizes, int n_in,
                              void* d_out, int out_size, void* d_ws, size_t ws_size,
                              hipStream_t stream) {
    const float* x  = (const float*)d_in[0];
    const float* Wq = (const float*)d_in[1];
    const float* Wk = (const float*)d_in[2];
    const float* Wv = (const float*)d_in[3];
    const float* Wo = (const float*)d_in[4];
    float* out = (float*)d_out;

    // ws layout (416 MiB total; proven to fit):
    // [Wt f16 32M][xh f16 64M][Qf f32 128M][Kf f32 128M][Vh f16 64M]
    // Yh (f16 64M) overlays xh — x is dead after the V GEMM.
    const size_t WT = (size_t)DIM * DIM * 2;
    const size_t XB = (size_t)NTOK * DIM * 2;
    const size_t QF = (size_t)NTOK * DIM * 4;
    const size_t VB = (size_t)NTOK * DIM * 2;
    const size_t NEED = WT + XB + 2 * QF + VB;    // 416 MiB
    if (ws_size < NEED) return;

    char* ws = (char*)d_ws;
    unsigned short* Wt = (unsigned short*)ws;
    unsigned short* xh = (unsigned short*)(ws + WT);
    float*          Qf = (float*)(ws + WT + XB);
    float*          Kf = (float*)(ws + WT + XB + QF);
    unsigned short* Vh = (unsigned short*)(ws + WT + XB + 2 * QF);
    unsigned short* Yh = xh;                      // overlay

    dim3 tgrid(DIM / 32, DIM / 32);
    const int ggrid = (NTOK / 256) * (DIM / 256) / 2;  // 256 persistent-pair blocks
    const int cblocks = (NTOK * DIM) / (256 * 8);

    convert_x<<<cblocks, 256, 0, stream>>>(x, xh);
    transpose_cvt4k<<<tgrid, 256, 0, stream>>>(Wq, Wt);
    gemm_nt_256<0><<<ggrid, 512, 0, stream>>>(xh, Wt, Qf, NTOK, DIM, DIM);
    transpose_cvt4k<<<tgrid, 256, 0, stream>>>(Wk, Wt);
    gemm_nt_256<0><<<ggrid, 512, 0, stream>>>(xh, Wt, Kf, NTOK, DIM, DIM);
    transpose_cvt4k<<<tgrid, 256, 0, stream>>>(Wv, Wt);
    gemm_nt_256<1><<<ggrid, 512, 0, stream>>>(xh, Wt, Vh, NTOK, DIM, DIM);
    attn_kernel<<<NTOK, 256, 0, stream>>>(Qf, Kf, Vh, Yh);   // Yh overlays xh
    transpose_cvt4k<<<tgrid, 256, 0, stream>>>(Wo, Wt);
    gemm_nt_256<0><<<ggrid, 512, 0, stream>>>(Yh, Wt, out, NTOK, DIM, DIM);
}

// Round 6
// 1473.444 us; speedup vs baseline: 1.0752x; 1.0752x over previous
//
#include <hip/hip_runtime.h>

#define DIM   4096
#define NTOK  8192
#define NH    32
#define HD    128

typedef _Float16 f16x8 __attribute__((ext_vector_type(8)));
typedef float    f32x4 __attribute__((ext_vector_type(4)));

__device__ __forceinline__ unsigned short f2h(float f) {
    _Float16 h = (_Float16)f;                    // RTNE
    return __builtin_bit_cast(unsigned short, h);
}
__device__ __forceinline__ float h2f(unsigned short u) {
    return (float)__builtin_bit_cast(_Float16, u);
}

// async 16B/lane global->LDS. LDS dest is wave-uniform base; HW scatters lane L to base + 16*L.
__device__ __forceinline__ void async_ld16(const unsigned short* g, unsigned short* l) {
    __builtin_amdgcn_global_load_lds(
        (const __attribute__((address_space(1))) unsigned int*)g,
        (__attribute__((address_space(3))) unsigned int*)l,
        16, 0, 0);
}

// ---------------------------------------------------------------------------
// x fp32 -> f16, elementwise. 8 elems/thread.
// ---------------------------------------------------------------------------
__global__ __launch_bounds__(256)
void convert_x(const float* __restrict__ in, unsigned short* __restrict__ out) {
    const size_t i = ((size_t)blockIdx.x * 256 + threadIdx.x) * 8;
    float4 a = *(const float4*)(in + i);
    float4 b = *(const float4*)(in + i + 4);
    ushort4 o0 = { f2h(a.x), f2h(a.y), f2h(a.z), f2h(a.w) };
    ushort4 o1 = { f2h(b.x), f2h(b.y), f2h(b.z), f2h(b.w) };
    *(ushort4*)(out + i)     = o0;
    *(ushort4*)(out + i + 4) = o1;
}

// ---------------------------------------------------------------------------
// W fp32 [k][n] -> Wt f16 [n][k], 4096x4096
// ---------------------------------------------------------------------------
__global__ __launch_bounds__(256)
void transpose_cvt4k(const float* __restrict__ in, unsigned short* __restrict__ out) {
    __shared__ unsigned short tile[32][33];
    const int tx = threadIdx.x & 31;
    const int ty = threadIdx.x >> 5;       // 0..7
    const int n0 = blockIdx.x * 32;
    const int k0 = blockIdx.y * 32;
#pragma unroll
    for (int i = 0; i < 4; ++i)
        tile[ty + i * 8][tx] = f2h(in[(size_t)(k0 + ty + i * 8) * DIM + n0 + tx]);
    __syncthreads();
#pragma unroll
    for (int i = 0; i < 4; ++i)
        out[(size_t)(n0 + ty + i * 8) * DIM + k0 + tx] = tile[tx][ty + i * 8];
}

// ---------------------------------------------------------------------------
// NT GEMM, 256x256 tile, BK=64, 8 waves (2Mx4N), pipelined cluster schedule,
// persistent-pair blocks.  ROUND-5: reverted to the round-3 16x16x32 MFMA
// configuration (measured 266 us/GEMM, SQ_LDS_BANK_CONFLICT = 0).  The
// round-4 32x32x16 variant measured 2.5e7 conflict-cycles (+24 us) despite a
// bank-model that predicts conflict-free — shape change shelved until the
// ds_read_b128 servicing model for that frag geometry is understood.
// ---------------------------------------------------------------------------
#define BARRIER() do { __builtin_amdgcn_sched_barrier(0); \
                       __builtin_amdgcn_s_barrier();      \
                       __builtin_amdgcn_sched_barrier(0); } while (0)
#define VMCNT6()  asm volatile("s_waitcnt vmcnt(6)" ::: "memory")

template <int Q>
__device__ __forceinline__ void mfma_quad(f32x4 (&acc)[8][4],
                                          const f16x8 (&aQ)[2][2],
                                          const f16x8 (&bF)[4][2]) {
    __builtin_amdgcn_s_setprio(1);
#pragma unroll
    for (int i2 = 0; i2 < 2; ++i2)
#pragma unroll
        for (int j = 0; j < 4; ++j)
#pragma unroll
            for (int ks = 0; ks < 2; ++ks)
                acc[2 * Q + i2][j] = __builtin_amdgcn_mfma_f32_16x16x32_f16(
                    aQ[i2][ks], bF[j][ks], acc[2 * Q + i2][j], 0, 0, 0);
    __builtin_amdgcn_s_setprio(0);
}

template <int OUT_F16>
__global__ __launch_bounds__(512, 2)
void gemm_nt_256(const unsigned short* __restrict__ A,
                 const unsigned short* __restrict__ Bt,
                 void* __restrict__ C, int M, int N, int K) {
    __shared__ unsigned short sA[2 * 256 * 64];   // 64 KiB
    __shared__ unsigned short sB[2 * 256 * 64];   // 64 KiB

    // persistent-pair mapping: nwg = (M/256)*(N/256)/2 blocks, pair along M.
    const int bid     = blockIdx.x;
    const int per_xcd = gridDim.x >> 3;           // 32
    const int wg      = (bid & 7) * per_xcd + (bid >> 3);
    const int m_pairs = M >> 9;                   // 16
    const int n_idx   = wg / m_pairs;
    const int m_pair  = wg % m_pairs;
    const int n0      = n_idx * 256;

    const int t    = threadIdx.x;
    const int w    = t >> 6;
    const int lane = t & 63;
    const int wm   = w >> 2;              // 0..1  (128 rows of C per wave)
    const int wn   = w & 3;               // 0..3  (64 cols of C per wave)
    const int fr   = lane & 15;           // fragment row
    const int kq   = (lane >> 4) << 3;    // lane's k offset within 32 (f16 units)
    const int swz  = (fr & 7) << 3;       // read-side swizzle (shorts); row&7 == fr&7
    const int c0   = kq ^ swz;            // ks=0 swizzled col
    const int c1   = (32 + kq) ^ swz;     // ks=1 swizzled col

    // staging: thread t covers LDS (row = t>>3 within slab, chunk = t&7).
    // Source chunk pre-swizzled so linear LDS + swizzled ds_read match.
    const int rowt = t >> 3;
    const int cSw8 = ((t & 7) ^ (rowt & 7)) << 3;
    unsigned short* dA = sA + w * 512;    // wave-uniform LDS base (1 KiB/wave/slab)
    unsigned short* dB = sB + w * 512;
    const unsigned short* pA0 = sA + (wm * 128 + fr) * 64;
    const unsigned short* pB0 = sB + (wn * 64  + fr) * 64;

    const int KT = K >> 6;                // 64 K-tiles

    f32x4 acc[8][4];
    f16x8 aA[2][2], aB[2][2], bF[4][2];

#define STA(srcT, dpar, r0) async_ld16(gA + (size_t)(r0) * K + (size_t)(srcT) * 64, \
                                       dA + (dpar) * 16384 + (r0) * 64)
#define STB(srcT, dpar, r0) async_ld16(gB + (size_t)(r0) * K + (size_t)(srcT) * 64, \
                                       dB + (dpar) * 16384 + (r0) * 64)
#define LDF(p, off) (*(const f16x8*)(const void*)((p) + (off)))

    for (int tt = 0; tt < 2; ++tt) {
        const int m0 = (m_pair * 2 + tt) * 256;
        const unsigned short* gA = A  + (size_t)(m0 + rowt) * K + cSw8;
        const unsigned short* gB = Bt + (size_t)(n0 + rowt) * K + cSw8;

#pragma unroll
        for (int i = 0; i < 8; ++i)
#pragma unroll
            for (int j = 0; j < 4; ++j) acc[i][j] = (f32x4){0.f, 0.f, 0.f, 0.f};

        // prologue: tile0 complete (8 slabs) + tile1 {Bx4, A rows 0-63/128-191}.
        // For tt=1 this is issued AFTER tile0's C-stores: vmcnt(6) drains the
        // stores plus the oldest 8 loads, leaving exactly the 6 partials.
        STA(0, 0, 0); STA(0, 0, 64); STA(0, 0, 128); STA(0, 0, 192);
        STB(0, 0, 0); STB(0, 0, 64); STB(0, 0, 128); STB(0, 0, 192);
        STB(1, 1, 0); STB(1, 1, 64); STB(1, 1, 128); STB(1, 1, 192);
        STA(1, 1, 0); STA(1, 1, 128);
        VMCNT6();
        BARRIER();

#define KTILE(T, BUF) do {                                                        \
    const int T1c = ((T) + 1 < KT) ? (T) + 1 : KT - 1;  /* clamp: dest never read */ \
    const int T2c = ((T) + 2 < KT) ? (T) + 2 : KT - 1;                            \
    const unsigned short* pa = pA0 + (BUF) * 16384;                               \
    const unsigned short* pb = pB0 + (BUF) * 16384;                               \
    /* tile start: full B (8 reads) + A-quadrant0 (4 reads); stage A'(T+1) */     \
    bF[0][0] = LDF(pb,        c0); bF[0][1] = LDF(pb,        c1);                 \
    bF[1][0] = LDF(pb, 1024 + c0); bF[1][1] = LDF(pb, 1024 + c1);                 \
    bF[2][0] = LDF(pb, 2048 + c0); bF[2][1] = LDF(pb, 2048 + c1);                 \
    bF[3][0] = LDF(pb, 3072 + c0); bF[3][1] = LDF(pb, 3072 + c1);                 \
    aA[0][0] = LDF(pa,        c0); aA[0][1] = LDF(pa,        c1);                 \
    aA[1][0] = LDF(pa, 1024 + c0); aA[1][1] = LDF(pa, 1024 + c1);                 \
    STA(T1c, (BUF) ^ 1, 64); STA(T1c, (BUF) ^ 1, 192);                            \
    mfma_quad<0>(acc, aA, bF);                                                    \
    /* prefetch quadrant1 A during cluster0 */                                    \
    aB[0][0] = LDF(pa, 2048 + c0); aB[0][1] = LDF(pa, 2048 + c1);                 \
    aB[1][0] = LDF(pa, 3072 + c0); aB[1][1] = LDF(pa, 3072 + c1);                 \
    BARRIER();  /* #1: B reads drained (cluster0) before B staging lands */       \
    STB(T2c, (BUF), 0);   STB(T2c, (BUF), 64);                                    \
    STB(T2c, (BUF), 128); STB(T2c, (BUF), 192);                                   \
    mfma_quad<1>(acc, aB, bF);                                                    \
    /* prefetch quadrant2 A during cluster1 */                                    \
    aA[0][0] = LDF(pa, 4096 + c0); aA[0][1] = LDF(pa, 4096 + c1);                 \
    aA[1][0] = LDF(pa, 5120 + c0); aA[1][1] = LDF(pa, 5120 + c1);                 \
    BARRIER();  /* #2: A q0/q1 reads drained (cluster1) before A staging lands */ \
    STA(T2c, (BUF), 0); STA(T2c, (BUF), 128);                                     \
    mfma_quad<2>(acc, aA, bF);                                                    \
    /* prefetch quadrant3 A during cluster2 (rows 96-127: never staged in-tile) */\
    aB[0][0] = LDF(pa, 6144 + c0); aB[0][1] = LDF(pa, 6144 + c1);                 \
    aB[1][0] = LDF(pa, 7168 + c0); aB[1][1] = LDF(pa, 7168 + c1);                 \
    mfma_quad<3>(acc, aB, bF);                                                    \
    VMCNT6();                                                                     \
    BARRIER();  /* #3: closing — next tile's reads see drained staging */         \
} while (0)

        for (int it = 0; it < (KT >> 1); ++it) {
            const int kt = it << 1;
            KTILE(kt, 0);
            KTILE(kt + 1, 1);
        }
#undef KTILE

        // epilogue: C/D layout col = lane&15, row = (lane>>4)*4 + reg.
        // Stores issue here; tt=1's prologue loads follow immediately and the
        // prologue VMCNT6 covers both (stores drain under tile1's staging).
        const int col0 = n0 + wn * 64 + fr;
        const int row0 = m0 + wm * 128 + (lane >> 4) * 4;
#pragma unroll
        for (int i = 0; i < 8; ++i) {
#pragma unroll
            for (int r = 0; r < 4; ++r) {
                const size_t row = (size_t)(row0 + i * 16 + r);
#pragma unroll
                for (int j = 0; j < 4; ++j) {
                    const size_t idx = row * (size_t)N + (size_t)(col0 + j * 16);
                    if (OUT_F16) ((unsigned short*)C)[idx] = f2h(acc[i][j][r]);
                    else         ((float*)C)[idx]          = acc[i][j][r];
                }
            }
        }
    }
#undef STA
#undef STB
#undef LDF
}

// ---------------------------------------------------------------------------
// Per-token head-mixing attention: S = Q Kt (32x32), softmax rows, y = S V.
// One block per token. Q,K fp32 (precision), V f16, y f16.
// sQ/sK float4-slot XOR-swizzle p = c ^ ((row>>1)&7) — removed the 16-way
// score-phase bank conflict (1.34e8 -> ~0 conflict-cycles, round-1 verified).
// Round-5: softmax parallelized across all 256 threads (8 lanes/row, 4 cols
// each, __shfl_xor over the 8-lane group) — replaces the 32-thread serial
// 3x32-iteration version (224 lanes idle, Common-mistake #6).
// ---------------------------------------------------------------------------
__global__ __launch_bounds__(256)
void attn_kernel(const float* __restrict__ Q, const float* __restrict__ K,
                 const unsigned short* __restrict__ V, unsigned short* __restrict__ Y) {
    __shared__ float sQ[NH * HD];               // 16 KB (float4-slot swizzled)
    __shared__ float sK[NH * HD];               // 16 KB (float4-slot swizzled)
    __shared__ unsigned short sV[NH * HD];      // 8 KB
    __shared__ float sS[NH * 33];               // 32x33 (padded)

    const int n = blockIdx.x;
    const int t = threadIdx.x;
    const size_t base = (size_t)n * DIM;

    const float4* gQ = (const float4*)(Q + base);
    const float4* gK = (const float4*)(K + base);
#pragma unroll
    for (int i = 0; i < 4; ++i) {
        const int f = t + 256 * i;
        const int r = f >> 5;                   // row 0..31
        const int p = (f & 31) ^ ((r >> 1) & 7);  // swizzled float4 slot
        ((float4*)sQ)[r * 32 + p] = gQ[f];
        ((float4*)sK)[r * 32 + p] = gK[f];
    }
    const float4* gV = (const float4*)(V + base);
#pragma unroll
    for (int i = 0; i < 2; ++i)
        ((float4*)sV)[t + 256 * i] = gV[t + 256 * i];
    __syncthreads();

    // scores: 16x16 thread grid, each thread a 2x2 block of S
    {
        const int th = (t >> 4) * 2;
        const int tg = (t & 15) * 2;
        const int sq = (th >> 1) & 7;           // th, th+1 share (th even)
        const int sk = (tg >> 1) & 7;
        float s00 = 0.f, s01 = 0.f, s10 = 0.f, s11 = 0.f;
        const float4* q0 = (const float4*)(sQ + th * HD);
        const float4* q1 = (const float4*)(sQ + (th + 1) * HD);
        const float4* k0 = (const float4*)(sK + tg * HD);
        const float4* k1 = (const float4*)(sK + (tg + 1) * HD);
#pragma unroll 4
        for (int d = 0; d < HD / 4; ++d) {
            float4 a0 = q0[d ^ sq], a1 = q1[d ^ sq];
            float4 b0 = k0[d ^ sk], b1 = k1[d ^ sk];
            s00 += a0.x * b0.x + a0.y * b0.y + a0.z * b0.z + a0.w * b0.w;
            s01 += a0.x * b1.x + a0.y * b1.y + a0.z * b1.z + a0.w * b1.w;
            s10 += a1.x * b0.x + a1.y * b0.y + a1.z * b0.z + a1.w * b0.w;
            s11 += a1.x * b1.x + a1.y * b1.y + a1.z * b1.z + a1.w * b1.w;
        }
        sS[th * 33 + tg] = s00;       sS[th * 33 + tg + 1] = s01;
        sS[(th + 1) * 33 + tg] = s10; sS[(th + 1) * 33 + tg + 1] = s11;
    }
    __syncthreads();

    // parallel row softmax: 8 lanes per row, 4 cols each (no 1/sqrt(d) scale)
    {
        const int row = t >> 3;                 // 0..31
        const int j   = t & 7;
        float v0 = sS[row * 33 + j],      v1 = sS[row * 33 + j + 8];
        float v2 = sS[row * 33 + j + 16], v3 = sS[row * 33 + j + 24];
        float m = fmaxf(fmaxf(v0, v1), fmaxf(v2, v3));
        m = fmaxf(m, __shfl_xor(m, 1));
        m = fmaxf(m, __shfl_xor(m, 2));
        m = fmaxf(m, __shfl_xor(m, 4));
        float e0 = __expf(v0 - m), e1 = __expf(v1 - m);
        float e2 = __expf(v2 - m), e3 = __expf(v3 - m);
        float s = e0 + e1 + e2 + e3;
        s += __shfl_xor(s, 1);
        s += __shfl_xor(s, 2);
        s += __shfl_xor(s, 4);
        const float inv = 1.f / s;
        sS[row * 33 + j]      = e0 * inv;
        sS[row * 33 + j + 8]  = e1 * inv;
        sS[row * 33 + j + 16] = e2 * inv;
        sS[row * 33 + j + 24] = e3 * inv;
    }
    __syncthreads();

    // y[h][d] = sum_g S[h][g] * V[g][d]; thread task: 2 heads x 4 d
#pragma unroll
    for (int e = 0; e < 2; ++e) {
        const int task = t + e * 256;          // 0..511
        const int h0 = (task >> 5) * 2;        // heads h0, h0+1
        const int dg = (task & 31) * 4;        // d offset
        float a0x = 0, a0y = 0, a0z = 0, a0w = 0;
        float a1x = 0, a1y = 0, a1z = 0, a1w = 0;
#pragma unroll 4
        for (int g = 0; g < NH; ++g) {
            ushort4 uv = *(const ushort4*)(const void*)(sV + g * HD + dg);
            float vx = h2f(uv.x), vy = h2f(uv.y), vz = h2f(uv.z), vw = h2f(uv.w);
            float p0 = sS[h0 * 33 + g], p1 = sS[(h0 + 1) * 33 + g];
            a0x += p0 * vx; a0y += p0 * vy; a0z += p0 * vz; a0w += p0 * vw;
            a1x += p1 * vx; a1y += p1 * vy; a1z += p1 * vz; a1w += p1 * vw;
        }
        ushort4 o0 = { f2h(a0x), f2h(a0y), f2h(a0z), f2h(a0w) };
        ushort4 o1 = { f2h(a1x), f2h(a1y), f2h(a1z), f2h(a1w) };
        *(ushort4*)(void*)(Y + base + (size_t)h0 * HD + dg)       = o0;
        *(ushort4*)(void*)(Y + base + (size_t)(h0 + 1) * HD + dg) = o1;
    }
}

// ---------------------------------------------------------------------------
extern "C" void kernel_launch(void* const* d_in, const int* in_sizes, int n_in,
                              void* d_out, int out_size, void* d_ws, size_t ws_size,
                              hipStream_t stream) {
    const float* x  = (const float*)d_in[0];
    const float* Wq = (const float*)d_in[1];
    const float* Wk = (const float*)d_in[2];
    const float* Wv = (const float*)d_in[3];
    const float* Wo = (const float*)d_in[4];
    float* out = (float*)d_out;

    // ws layout (416 MiB total; proven to fit):
    // [Wt f16 32M][xh f16 64M][Qf f32 128M][Kf f32 128M][Vh f16 64M]
    // Yh (f16 64M) overlays xh — x is dead after the V GEMM.
    const size_t WT = (size_t)DIM * DIM * 2;
    const size_t XB = (size_t)NTOK * DIM * 2;
    const size_t QF = (size_t)NTOK * DIM * 4;
    const size_t VB = (size_t)NTOK * DIM * 2;
    const size_t NEED = WT + XB + 2 * QF + VB;    // 416 MiB
    if (ws_size < NEED) return;

    char* ws = (char*)d_ws;
    unsigned short* Wt = (unsigned short*)ws;
    unsigned short* xh = (unsigned short*)(ws + WT);
    float*          Qf = (float*)(ws + WT + XB);
    float*          Kf = (float*)(ws + WT + XB + QF);
    unsigned short* Vh = (unsigned short*)(ws + WT + XB + 2 * QF);
    unsigned short* Yh = xh;                      // overlay

    dim3 tgrid(DIM / 32, DIM / 32);
    const int ggrid = (NTOK / 256) * (DIM / 256) / 2;  // 256 persistent-pair blocks
    const int cblocks = (NTOK * DIM) / (256 * 8);

    convert_x<<<cblocks, 256, 0, stream>>>(x, xh);
    transpose_cvt4k<<<tgrid, 256, 0, stream>>>(Wq, Wt);
    gemm_nt_256<0><<<ggrid, 512, 0, stream>>>(xh, Wt, Qf, NTOK, DIM, DIM);
    transpose_cvt4k<<<tgrid, 256, 0, stream>>>(Wk, Wt);
    gemm_nt_256<0><<<ggrid, 512, 0, stream>>>(xh, Wt, Kf, NTOK, DIM, DIM);
    transpose_cvt4k<<<tgrid, 256, 0, stream>>>(Wv, Wt);
    gemm_nt_256<1><<<ggrid, 512, 0, stream>>>(xh, Wt, Vh, NTOK, DIM, DIM);
    attn_kernel<<<NTOK, 256, 0, stream>>>(Qf, Kf, Vh, Yh);   // Yh overlays xh
    transpose_cvt4k<<<tgrid, 256, 0, stream>>>(Wo, Wt);
    gemm_nt_256<0><<<ggrid, 512, 0, stream>>>(Yh, Wt, out, NTOK, DIM, DIM);
}

// Round 7
// 1409.808 us; speedup vs baseline: 1.1237x; 1.0451x over previous
//
#include <hip/hip_runtime.h>

#define DIM   4096
#define NTOK  8192
#define NH    32
#define HD    128

typedef _Float16 f16x8 __attribute__((ext_vector_type(8)));
typedef float    f32x4 __attribute__((ext_vector_type(4)));

__device__ __forceinline__ unsigned short f2h(float f) {
    _Float16 h = (_Float16)f;                    // RTNE
    return __builtin_bit_cast(unsigned short, h);
}
__device__ __forceinline__ float h2f(unsigned short u) {
    return (float)__builtin_bit_cast(_Float16, u);
}

// async 16B/lane global->LDS. LDS dest is wave-uniform base; HW scatters lane L to base + 16*L.
__device__ __forceinline__ void async_ld16(const unsigned short* g, unsigned short* l) {
    __builtin_amdgcn_global_load_lds(
        (const __attribute__((address_space(1))) unsigned int*)g,
        (__attribute__((address_space(3))) unsigned int*)l,
        16, 0, 0);
}

// ---------------------------------------------------------------------------
// x fp32 -> f16, elementwise. 8 elems/thread.
// ---------------------------------------------------------------------------
__global__ __launch_bounds__(256)
void convert_x(const float* __restrict__ in, unsigned short* __restrict__ out) {
    const size_t i = ((size_t)blockIdx.x * 256 + threadIdx.x) * 8;
    float4 a = *(const float4*)(in + i);
    float4 b = *(const float4*)(in + i + 4);
    ushort4 o0 = { f2h(a.x), f2h(a.y), f2h(a.z), f2h(a.w) };
    ushort4 o1 = { f2h(b.x), f2h(b.y), f2h(b.z), f2h(b.w) };
    *(ushort4*)(out + i)     = o0;
    *(ushort4*)(out + i + 4) = o1;
}

// ---------------------------------------------------------------------------
// W fp32 [k][n] -> Wt f16 [n][k], 4096x4096
// ---------------------------------------------------------------------------
__global__ __launch_bounds__(256)
void transpose_cvt4k(const float* __restrict__ in, unsigned short* __restrict__ out) {
    __shared__ unsigned short tile[32][33];
    const int tx = threadIdx.x & 31;
    const int ty = threadIdx.x >> 5;       // 0..7
    const int n0 = blockIdx.x * 32;
    const int k0 = blockIdx.y * 32;
#pragma unroll
    for (int i = 0; i < 4; ++i)
        tile[ty + i * 8][tx] = f2h(in[(size_t)(k0 + ty + i * 8) * DIM + n0 + tx]);
    __syncthreads();
#pragma unroll
    for (int i = 0; i < 4; ++i)
        out[(size_t)(n0 + ty + i * 8) * DIM + k0 + tx] = tile[tx][ty + i * 8];
}

// ---------------------------------------------------------------------------
// NT GEMM, 256x256 tile, BK=64, 8 waves (2Mx4N), pipelined cluster schedule,
// persistent-pair blocks, 16x16x32 MFMA (round-5 verified: 272-276 us,
// SQ_LDS_BANK_CONFLICT = 0).  K-loop untouched this round.
// Round-6: Q/K GEMMs now write f16 (OUT_F16=1) — halves their WRITE_SIZE
// and attn's Q/K read traffic; precision impact ~1e-3 relative on scores.
// ---------------------------------------------------------------------------
#define BARRIER() do { __builtin_amdgcn_sched_barrier(0); \
                       __builtin_amdgcn_s_barrier();      \
                       __builtin_amdgcn_sched_barrier(0); } while (0)
#define VMCNT6()  asm volatile("s_waitcnt vmcnt(6)" ::: "memory")

template <int Q>
__device__ __forceinline__ void mfma_quad(f32x4 (&acc)[8][4],
                                          const f16x8 (&aQ)[2][2],
                                          const f16x8 (&bF)[4][2]) {
    __builtin_amdgcn_s_setprio(1);
#pragma unroll
    for (int i2 = 0; i2 < 2; ++i2)
#pragma unroll
        for (int j = 0; j < 4; ++j)
#pragma unroll
            for (int ks = 0; ks < 2; ++ks)
                acc[2 * Q + i2][j] = __builtin_amdgcn_mfma_f32_16x16x32_f16(
                    aQ[i2][ks], bF[j][ks], acc[2 * Q + i2][j], 0, 0, 0);
    __builtin_amdgcn_s_setprio(0);
}

template <int OUT_F16>
__global__ __launch_bounds__(512, 2)
void gemm_nt_256(const unsigned short* __restrict__ A,
                 const unsigned short* __restrict__ Bt,
                 void* __restrict__ C, int M, int N, int K) {
    __shared__ unsigned short sA[2 * 256 * 64];   // 64 KiB
    __shared__ unsigned short sB[2 * 256 * 64];   // 64 KiB

    // persistent-pair mapping: nwg = (M/256)*(N/256)/2 blocks, pair along M.
    const int bid     = blockIdx.x;
    const int per_xcd = gridDim.x >> 3;           // 32
    const int wg      = (bid & 7) * per_xcd + (bid >> 3);
    const int m_pairs = M >> 9;                   // 16
    const int n_idx   = wg / m_pairs;
    const int m_pair  = wg % m_pairs;
    const int n0      = n_idx * 256;

    const int t    = threadIdx.x;
    const int w    = t >> 6;
    const int lane = t & 63;
    const int wm   = w >> 2;              // 0..1  (128 rows of C per wave)
    const int wn   = w & 3;               // 0..3  (64 cols of C per wave)
    const int fr   = lane & 15;           // fragment row
    const int kq   = (lane >> 4) << 3;    // lane's k offset within 32 (f16 units)
    const int swz  = (fr & 7) << 3;       // read-side swizzle (shorts); row&7 == fr&7
    const int c0   = kq ^ swz;            // ks=0 swizzled col
    const int c1   = (32 + kq) ^ swz;     // ks=1 swizzled col

    // staging: thread t covers LDS (row = t>>3 within slab, chunk = t&7).
    // Source chunk pre-swizzled so linear LDS + swizzled ds_read match.
    const int rowt = t >> 3;
    const int cSw8 = ((t & 7) ^ (rowt & 7)) << 3;
    unsigned short* dA = sA + w * 512;    // wave-uniform LDS base (1 KiB/wave/slab)
    unsigned short* dB = sB + w * 512;
    const unsigned short* pA0 = sA + (wm * 128 + fr) * 64;
    const unsigned short* pB0 = sB + (wn * 64  + fr) * 64;

    const int KT = K >> 6;                // 64 K-tiles

    f32x4 acc[8][4];
    f16x8 aA[2][2], aB[2][2], bF[4][2];

#define STA(srcT, dpar, r0) async_ld16(gA + (size_t)(r0) * K + (size_t)(srcT) * 64, \
                                       dA + (dpar) * 16384 + (r0) * 64)
#define STB(srcT, dpar, r0) async_ld16(gB + (size_t)(r0) * K + (size_t)(srcT) * 64, \
                                       dB + (dpar) * 16384 + (r0) * 64)
#define LDF(p, off) (*(const f16x8*)(const void*)((p) + (off)))

    for (int tt = 0; tt < 2; ++tt) {
        const int m0 = (m_pair * 2 + tt) * 256;
        const unsigned short* gA = A  + (size_t)(m0 + rowt) * K + cSw8;
        const unsigned short* gB = Bt + (size_t)(n0 + rowt) * K + cSw8;

#pragma unroll
        for (int i = 0; i < 8; ++i)
#pragma unroll
            for (int j = 0; j < 4; ++j) acc[i][j] = (f32x4){0.f, 0.f, 0.f, 0.f};

        // prologue: tile0 complete (8 slabs) + tile1 {Bx4, A rows 0-63/128-191}.
        // For tt=1 this is issued AFTER tile0's C-stores: vmcnt(6) drains the
        // stores plus the oldest 8 loads, leaving exactly the 6 partials.
        STA(0, 0, 0); STA(0, 0, 64); STA(0, 0, 128); STA(0, 0, 192);
        STB(0, 0, 0); STB(0, 0, 64); STB(0, 0, 128); STB(0, 0, 192);
        STB(1, 1, 0); STB(1, 1, 64); STB(1, 1, 128); STB(1, 1, 192);
        STA(1, 1, 0); STA(1, 1, 128);
        VMCNT6();
        BARRIER();

#define KTILE(T, BUF) do {                                                        \
    const int T1c = ((T) + 1 < KT) ? (T) + 1 : KT - 1;  /* clamp: dest never read */ \
    const int T2c = ((T) + 2 < KT) ? (T) + 2 : KT - 1;                            \
    const unsigned short* pa = pA0 + (BUF) * 16384;                               \
    const unsigned short* pb = pB0 + (BUF) * 16384;                               \
    /* tile start: full B (8 reads) + A-quadrant0 (4 reads); stage A'(T+1) */     \
    bF[0][0] = LDF(pb,        c0); bF[0][1] = LDF(pb,        c1);                 \
    bF[1][0] = LDF(pb, 1024 + c0); bF[1][1] = LDF(pb, 1024 + c1);                 \
    bF[2][0] = LDF(pb, 2048 + c0); bF[2][1] = LDF(pb, 2048 + c1);                 \
    bF[3][0] = LDF(pb, 3072 + c0); bF[3][1] = LDF(pb, 3072 + c1);                 \
    aA[0][0] = LDF(pa,        c0); aA[0][1] = LDF(pa,        c1);                 \
    aA[1][0] = LDF(pa, 1024 + c0); aA[1][1] = LDF(pa, 1024 + c1);                 \
    STA(T1c, (BUF) ^ 1, 64); STA(T1c, (BUF) ^ 1, 192);                            \
    mfma_quad<0>(acc, aA, bF);                                                    \
    /* prefetch quadrant1 A during cluster0 */                                    \
    aB[0][0] = LDF(pa, 2048 + c0); aB[0][1] = LDF(pa, 2048 + c1);                 \
    aB[1][0] = LDF(pa, 3072 + c0); aB[1][1] = LDF(pa, 3072 + c1);                 \
    BARRIER();  /* #1: B reads drained (cluster0) before B staging lands */       \
    STB(T2c, (BUF), 0);   STB(T2c, (BUF), 64);                                    \
    STB(T2c, (BUF), 128); STB(T2c, (BUF), 192);                                   \
    mfma_quad<1>(acc, aB, bF);                                                    \
    /* prefetch quadrant2 A during cluster1 */                                    \
    aA[0][0] = LDF(pa, 4096 + c0); aA[0][1] = LDF(pa, 4096 + c1);                 \
    aA[1][0] = LDF(pa, 5120 + c0); aA[1][1] = LDF(pa, 5120 + c1);                 \
    BARRIER();  /* #2: A q0/q1 reads drained (cluster1) before A staging lands */ \
    STA(T2c, (BUF), 0); STA(T2c, (BUF), 128);                                     \
    mfma_quad<2>(acc, aA, bF);                                                    \
    /* prefetch quadrant3 A during cluster2 (rows 96-127: never staged in-tile) */\
    aB[0][0] = LDF(pa, 6144 + c0); aB[0][1] = LDF(pa, 6144 + c1);                 \
    aB[1][0] = LDF(pa, 7168 + c0); aB[1][1] = LDF(pa, 7168 + c1);                 \
    mfma_quad<3>(acc, aB, bF);                                                    \
    VMCNT6();                                                                     \
    BARRIER();  /* #3: closing — next tile's reads see drained staging */         \
} while (0)

        for (int it = 0; it < (KT >> 1); ++it) {
            const int kt = it << 1;
            KTILE(kt, 0);
            KTILE(kt + 1, 1);
        }
#undef KTILE

        // epilogue: C/D layout col = lane&15, row = (lane>>4)*4 + reg.
        // Stores issue here; tt=1's prologue loads follow immediately and the
        // prologue VMCNT6 covers both (stores drain under tile1's staging).
        const int col0 = n0 + wn * 64 + fr;
        const int row0 = m0 + wm * 128 + (lane >> 4) * 4;
#pragma unroll
        for (int i = 0; i < 8; ++i) {
#pragma unroll
            for (int r = 0; r < 4; ++r) {
                const size_t row = (size_t)(row0 + i * 16 + r);
#pragma unroll
                for (int j = 0; j < 4; ++j) {
                    const size_t idx = row * (size_t)N + (size_t)(col0 + j * 16);
                    if (OUT_F16) ((unsigned short*)C)[idx] = f2h(acc[i][j][r]);
                    else         ((float*)C)[idx]          = acc[i][j][r];
                }
            }
        }
    }
#undef STA
#undef STB
#undef LDF
}

// ---------------------------------------------------------------------------
// Per-token head-mixing attention: S = Q Kt (32x32), softmax rows, y = S V.
// One block per token.  Round-6: Q,K inputs are f16 (halved HBM read);
// converted to f32 ONCE during LDS staging, so the verified swizzled f32
// compute path (scores/softmax/PV) is unchanged.
// sQ/sK float4-slot XOR-swizzle p = c ^ ((row>>1)&7): the two float4 slots of
// each f16x8 chunk (2c, 2c+1) differ only in bit0, and the XOR mask is
// row-constant, so the swizzled pair stays a contiguous/adjacent slot pair.
// ---------------------------------------------------------------------------
__global__ __launch_bounds__(256)
void attn_kernel(const unsigned short* __restrict__ Q, const unsigned short* __restrict__ K,
                 const unsigned short* __restrict__ V, unsigned short* __restrict__ Y) {
    __shared__ float sQ[NH * HD];               // 16 KB (float4-slot swizzled)
    __shared__ float sK[NH * HD];               // 16 KB (float4-slot swizzled)
    __shared__ unsigned short sV[NH * HD];      // 8 KB
    __shared__ float sS[NH * 33];               // 32x33 (padded)

    const int n = blockIdx.x;
    const int t = threadIdx.x;
    const size_t base = (size_t)n * DIM;

    // stage Q,K: 4096 f16 each = 512 chunks of 8; cvt to f32, swizzled store
#pragma unroll
    for (int i = 0; i < 2; ++i) {
        const int c    = t + 256 * i;           // chunk 0..511
        const int r    = c >> 4;                // row 0..31
        const int col8 = c & 15;                // 8-elem chunk within row
        const int m    = (r >> 1) & 7;
        const int s0   = r * 32 + ((col8 * 2) ^ m);
        const int s1   = r * 32 + ((col8 * 2 + 1) ^ m);
        ushort4 q0 = ((const ushort4*)(Q + base))[c * 2];
        ushort4 q1 = ((const ushort4*)(Q + base))[c * 2 + 1];
        ushort4 k0 = ((const ushort4*)(K + base))[c * 2];
        ushort4 k1 = ((const ushort4*)(K + base))[c * 2 + 1];
        ((float4*)sQ)[s0] = (float4){ h2f(q0.x), h2f(q0.y), h2f(q0.z), h2f(q0.w) };
        ((float4*)sQ)[s1] = (float4){ h2f(q1.x), h2f(q1.y), h2f(q1.z), h2f(q1.w) };
        ((float4*)sK)[s0] = (float4){ h2f(k0.x), h2f(k0.y), h2f(k0.z), h2f(k0.w) };
        ((float4*)sK)[s1] = (float4){ h2f(k1.x), h2f(k1.y), h2f(k1.z), h2f(k1.w) };
    }
    const float4* gV = (const float4*)(V + base);
#pragma unroll
    for (int i = 0; i < 2; ++i)
        ((float4*)sV)[t + 256 * i] = gV[t + 256 * i];
    __syncthreads();

    // scores: 16x16 thread grid, each thread a 2x2 block of S
    {
        const int th = (t >> 4) * 2;
        const int tg = (t & 15) * 2;
        const int sq = (th >> 1) & 7;           // th, th+1 share (th even)
        const int sk = (tg >> 1) & 7;
        float s00 = 0.f, s01 = 0.f, s10 = 0.f, s11 = 0.f;
        const float4* q0 = (const float4*)(sQ + th * HD);
        const float4* q1 = (const float4*)(sQ + (th + 1) * HD);
        const float4* k0 = (const float4*)(sK + tg * HD);
        const float4* k1 = (const float4*)(sK + (tg + 1) * HD);
#pragma unroll 4
        for (int d = 0; d < HD / 4; ++d) {
            float4 a0 = q0[d ^ sq], a1 = q1[d ^ sq];
            float4 b0 = k0[d ^ sk], b1 = k1[d ^ sk];
            s00 += a0.x * b0.x + a0.y * b0.y + a0.z * b0.z + a0.w * b0.w;
            s01 += a0.x * b1.x + a0.y * b1.y + a0.z * b1.z + a0.w * b1.w;
            s10 += a1.x * b0.x + a1.y * b0.y + a1.z * b0.z + a1.w * b0.w;
            s11 += a1.x * b1.x + a1.y * b1.y + a1.z * b1.z + a1.w * b1.w;
        }
        sS[th * 33 + tg] = s00;       sS[th * 33 + tg + 1] = s01;
        sS[(th + 1) * 33 + tg] = s10; sS[(th + 1) * 33 + tg + 1] = s11;
    }
    __syncthreads();

    // parallel row softmax: 8 lanes per row, 4 cols each (no 1/sqrt(d) scale)
    {
        const int row = t >> 3;                 // 0..31
        const int j   = t & 7;
        float v0 = sS[row * 33 + j],      v1 = sS[row * 33 + j + 8];
        float v2 = sS[row * 33 + j + 16], v3 = sS[row * 33 + j + 24];
        float m = fmaxf(fmaxf(v0, v1), fmaxf(v2, v3));
        m = fmaxf(m, __shfl_xor(m, 1));
        m = fmaxf(m, __shfl_xor(m, 2));
        m = fmaxf(m, __shfl_xor(m, 4));
        float e0 = __expf(v0 - m), e1 = __expf(v1 - m);
        float e2 = __expf(v2 - m), e3 = __expf(v3 - m);
        float s = e0 + e1 + e2 + e3;
        s += __shfl_xor(s, 1);
        s += __shfl_xor(s, 2);
        s += __shfl_xor(s, 4);
        const float inv = 1.f / s;
        sS[row * 33 + j]      = e0 * inv;
        sS[row * 33 + j + 8]  = e1 * inv;
        sS[row * 33 + j + 16] = e2 * inv;
        sS[row * 33 + j + 24] = e3 * inv;
    }
    __syncthreads();

    // y[h][d] = sum_g S[h][g] * V[g][d]; thread task: 2 heads x 4 d
#pragma unroll
    for (int e = 0; e < 2; ++e) {
        const int task = t + e * 256;          // 0..511
        const int h0 = (task >> 5) * 2;        // heads h0, h0+1
        const int dg = (task & 31) * 4;        // d offset
        float a0x = 0, a0y = 0, a0z = 0, a0w = 0;
        float a1x = 0, a1y = 0, a1z = 0, a1w = 0;
#pragma unroll 4
        for (int g = 0; g < NH; ++g) {
            ushort4 uv = *(const ushort4*)(const void*)(sV + g * HD + dg);
            float vx = h2f(uv.x), vy = h2f(uv.y), vz = h2f(uv.z), vw = h2f(uv.w);
            float p0 = sS[h0 * 33 + g], p1 = sS[(h0 + 1) * 33 + g];
            a0x += p0 * vx; a0y += p0 * vy; a0z += p0 * vz; a0w += p0 * vw;
            a1x += p1 * vx; a1y += p1 * vy; a1z += p1 * vz; a1w += p1 * vw;
        }
        ushort4 o0 = { f2h(a0x), f2h(a0y), f2h(a0z), f2h(a0w) };
        ushort4 o1 = { f2h(a1x), f2h(a1y), f2h(a1z), f2h(a1w) };
        *(ushort4*)(void*)(Y + base + (size_t)h0 * HD + dg)       = o0;
        *(ushort4*)(void*)(Y + base + (size_t)(h0 + 1) * HD + dg) = o1;
    }
}

// ---------------------------------------------------------------------------
extern "C" void kernel_launch(void* const* d_in, const int* in_sizes, int n_in,
                              void* d_out, int out_size, void* d_ws, size_t ws_size,
                              hipStream_t stream) {
    const float* x  = (const float*)d_in[0];
    const float* Wq = (const float*)d_in[1];
    const float* Wk = (const float*)d_in[2];
    const float* Wv = (const float*)d_in[3];
    const float* Wo = (const float*)d_in[4];
    float* out = (float*)d_out;

    // ws layout (288 MiB total):
    // [Wt f16 32M][xh f16 64M][Qh f16 64M][Kh f16 64M][Vh f16 64M]
    // Yh (f16 64M) overlays xh — x is dead after the V GEMM.
    const size_t WT = (size_t)DIM * DIM * 2;
    const size_t XB = (size_t)NTOK * DIM * 2;
    const size_t QH = (size_t)NTOK * DIM * 2;
    const size_t NEED = WT + XB + 3 * QH;         // 288 MiB
    if (ws_size < NEED) return;

    char* ws = (char*)d_ws;
    unsigned short* Wt = (unsigned short*)ws;
    unsigned short* xh = (unsigned short*)(ws + WT);
    unsigned short* Qh = (unsigned short*)(ws + WT + XB);
    unsigned short* Kh = (unsigned short*)(ws + WT + XB + QH);
    unsigned short* Vh = (unsigned short*)(ws + WT + XB + 2 * QH);
    unsigned short* Yh = xh;                      // overlay

    dim3 tgrid(DIM / 32, DIM / 32);
    const int ggrid = (NTOK / 256) * (DIM / 256) / 2;  // 256 persistent-pair blocks
    const int cblocks = (NTOK * DIM) / (256 * 8);

    convert_x<<<cblocks, 256, 0, stream>>>(x, xh);
    transpose_cvt4k<<<tgrid, 256, 0, stream>>>(Wq, Wt);
    gemm_nt_256<1><<<ggrid, 512, 0, stream>>>(xh, Wt, Qh, NTOK, DIM, DIM);
    transpose_cvt4k<<<tgrid, 256, 0, stream>>>(Wk, Wt);
    gemm_nt_256<1><<<ggrid, 512, 0, stream>>>(xh, Wt, Kh, NTOK, DIM, DIM);
    transpose_cvt4k<<<tgrid, 256, 0, stream>>>(Wv, Wt);
    gemm_nt_256<1><<<ggrid, 512, 0, stream>>>(xh, Wt, Vh, NTOK, DIM, DIM);
    attn_kernel<<<NTOK, 256, 0, stream>>>(Qh, Kh, Vh, Yh);   // Yh overlays xh
    transpose_cvt4k<<<tgrid, 256, 0, stream>>>(Wo, Wt);
    gemm_nt_256<0><<<ggrid, 512, 0, stream>>>(Yh, Wt, out, NTOK, DIM, DIM);
}